// Round 12
// baseline (210.909 us; speedup 1.0000x reference)
//
#include <hip/hip_runtime.h>

// B=4, C=256, H=W=64 (N=4096). QKV 1x1conv -> spatial attention (softmax over
// j only => independent per-64-key-chunk softmax) -> channel LayerNorm.
// f16 MFMA 32x32x16, fp32 accumulation.
//
// R18: attn reverted to R16 (kernel-level evidence: 105.9us x3 vs R17's
// 111.1; totals' spread was non-attn noise). gemm rewritten: wconv emits W
// in FRAGMENT-MAJOR order (Wf[pr][q][ot][ks][lane][8]) so gemm waves load
// their MFMA B-fragments directly from global as 16 coalesced 1KB loads,
// prefetched one full q-round ahead (in flight across lgkm-only LBARs).
// Deletes the Wh LDS tile (33.8KB) + its commit/re-read traffic + 1 barrier
// per round -> LDS 44KB -> launch_bounds(256,3): 3 blocks/CU, entire 768
// grid co-resident in ONE pass (no tail). Regs ~130 < 170 cap (no spill).
// merge_ln unchanged (proven).

#define CDIM 256
#define NPOS 4096
#define BATCH 4
#define EPSV 1e-5f

typedef _Float16 f16;
typedef __attribute__((ext_vector_type(4))) _Float16 f16x4;
typedef __attribute__((ext_vector_type(8))) _Float16 f16x8;
typedef __attribute__((ext_vector_type(4))) float f32x4;
typedef __attribute__((ext_vector_type(16))) float f32x16;

#define WST       264   // f16; 528B = 33*16 -> b128-aligned rows
#define QK_STRIDE 264   // f16 K-tile rows
#define V_STRIDE  72    // f16 Vs/P rows; 144B = 9*16
#define DQ_STRIDE 72
#define F_STRIDE  68    // merge kernel LDS stride (f32)

// LDS-only barrier: prior LDS ops complete, global loads stay in flight.
#define LBAR() asm volatile("s_waitcnt lgkmcnt(0)\n\ts_barrier" ::: "memory")

// MFMA 32x32x16 f16:
//   A: lane l holds A[m=l&31][k=(l>>5)*8+j]
//   B: lane l holds B[k=(l>>5)*8+j][n=l&31]   (same register layout as A)
//   C/D: lane l, reg r -> row m=(r&3)+8*(r>>2)+4*(l>>5), col n=l&31
//
// Fragment-major W: Wf[(pr*8 + q*2 + ot)*8192 + (ks*64 + lane)*8], lane l
// covering W[o = q*64 + ot*32 + (l&31)][c = ks*16 + (l>>5)*8 + 0..7].

static __device__ __forceinline__ f16x8 cvt8(const float* __restrict__ p) {
    float4 w0 = *(const float4*)p;
    float4 w1 = *(const float4*)(p + 4);
    f16x8 r;
    r[0] = (f16)w0.x; r[1] = (f16)w0.y; r[2] = (f16)w0.z; r[3] = (f16)w0.w;
    r[4] = (f16)w1.x; r[5] = (f16)w1.y; r[6] = (f16)w1.z; r[7] = (f16)w1.w;
    return r;
}

// ---------------------------------------------------------------------------
// wconv: 24 blocks = pr*8 + q*2 + ot. Converts fp32 weights -> fragment-major
// f16 Wf. One-time 384KB; scattered 32B reads are L2-absorbed.
// ---------------------------------------------------------------------------
__global__ __launch_bounds__(256, 4) void wconv_kernel(
    const float* __restrict__ qw, const float* __restrict__ kw,
    const float* __restrict__ vw, f16* __restrict__ Wf)
{
    const int id = blockIdx.x;           // 0..23
    const int t  = threadIdx.x;
    const int pr = id >> 3;
    const int q  = (id >> 1) & 3;
    const int ot = id & 1;
    const float* W = (pr == 0 ? qw : pr == 1 ? kw : vw);
    f16* D = Wf + (size_t)id * 8192;
    #pragma unroll
    for (int i = 0; i < 4; ++i) {
        int idx = t + i * 256;           // 0..1023 = ks*64 + l
        int ks = idx >> 6, l = idx & 63;
        const float* src = W + (size_t)(q * 64 + ot * 32 + (l & 31)) * CDIM
                             + ks * 16 + (l >> 5) * 8;
        *(f16x8*)(D + (size_t)idx * 8) = cvt8(src);
    }
}

// ---------------------------------------------------------------------------
// gemm: 768 blocks = (pr, b, ptile), 256 thr, (256,3) -> 3 blocks/CU, one
// pass. Xs staged from fp32 x (transpose in staging, proven); W fragments
// read DIRECTLY from fragment-major global, prefetched one q-round ahead
// (in flight across lgkm-only barriers). No Wh LDS, no W barrier.
// MFMA loop operands + Ds epilogue + stores identical to proven kernel.
// ---------------------------------------------------------------------------
__global__ __launch_bounds__(256, 3) void gemm_kernel(
    const float* __restrict__ x1, const float* __restrict__ x2,
    const f16* __restrict__ Wf,
    const float* __restrict__ qb, const float* __restrict__ kb,
    const float* __restrict__ vb,
    f16* __restrict__ Qg, f16* __restrict__ Kg, f16* __restrict__ Vg)
{
    __shared__ f16 Xs[64 * WST];          // 33792 B
    __shared__ f16 Ds[64 * DQ_STRIDE];    //  9216 B
    __shared__ float biasS[256];          //  1024 B   (total 44032 B)

    const int id = blockIdx.x;
    const int pr  = id >> 8;
    const int rem = id & 255;
    const int b   = rem >> 6;
    const int p0  = (rem & 63) << 6;
    const float* xsrc = ((pr == 0) ? x1 : x2) + (size_t)b * CDIM * NPOS + p0;
    const float* bias = (pr == 0) ? qb : (pr == 1) ? kb : vb;

    const int t = threadIdx.x, w = t >> 6, l = t & 63, lm = l & 31, lh = l >> 5;
    const int pt = w & 1, ot = w >> 1;

    const f16* Wfp = Wf + (size_t)pr * 65536 + (size_t)ot * 8192;

    biasS[t] = bias[t];
    // Xs[p][c] <- x[b][c][p0+p], fp32->f16 (transpose via staging, proven)
    #pragma unroll
    for (int g = 0; g < 8; ++g) {
        f16x8 h;
        #pragma unroll
        for (int j = 0; j < 8; ++j)
            h[j] = (f16)xsrc[(size_t)(w * 64 + g * 8 + j) * NPOS + l];
        *(f16x8*)&Xs[l * WST + w * 64 + g * 8] = h;
    }

    // q=0 W fragments (each: 64 lanes x 16B = 1KB contiguous per instr)
    f16x8 wf[16];
    #pragma unroll
    for (int ks = 0; ks < 16; ++ks)
        wf[ks] = *(const f16x8*)(Wfp + (size_t)ks * 512 + l * 8);

    __syncthreads();   // Xs ready

    for (int q = 0; q < 4; ++q) {
        f32x16 accA = {}, accB = {};
        #pragma unroll
        for (int ks = 0; ks < 16; ks += 2) {
            f16x8 x0  = *(const f16x8*)&Xs[(pt * 32 + lm) * WST + ks * 16 + lh * 8];
            f16x8 x1v = *(const f16x8*)&Xs[(pt * 32 + lm) * WST + (ks + 1) * 16 + lh * 8];
            if (pr < 2) {
                accA = __builtin_amdgcn_mfma_f32_32x32x16_f16(x0, wf[ks], accA, 0, 0, 0);
                accB = __builtin_amdgcn_mfma_f32_32x32x16_f16(x1v, wf[ks + 1], accB, 0, 0, 0);
            } else {
                accA = __builtin_amdgcn_mfma_f32_32x32x16_f16(wf[ks], x0, accA, 0, 0, 0);
                accB = __builtin_amdgcn_mfma_f32_32x32x16_f16(wf[ks + 1], x1v, accB, 0, 0, 0);
            }
        }

        // prefetch next round's W fragments (overlap Ds + store phases)
        if (q < 3) {
            #pragma unroll
            for (int ks = 0; ks < 16; ++ks)
                wf[ks] = *(const f16x8*)(Wfp + (size_t)(q + 1) * 16384
                                             + (size_t)ks * 512 + l * 8);
        }

        if (pr < 2) {
            int o_l = ot * 32 + lm;
            float bv = biasS[q * 64 + o_l];
            #pragma unroll
            for (int r = 0; r < 16; ++r) {
                int p_l = pt * 32 + (r & 3) + 8 * (r >> 2) + 4 * lh;
                Ds[p_l * DQ_STRIDE + o_l] = (f16)(accA[r] + accB[r] + bv);
            }
        } else {
            #pragma unroll
            for (int r = 0; r < 16; ++r) {
                int o_l = ot * 32 + (r & 3) + 8 * (r >> 2) + 4 * lh;
                Ds[o_l * DQ_STRIDE + pt * 32 + lm] =
                    (f16)(accA[r] + accB[r] + biasS[q * 64 + o_l]);
            }
        }
        LBAR();

        #pragma unroll
        for (int j = 0; j < 2; ++j) {
            int row = (t >> 3) + j * 32;
            int cc  = (t & 7) * 8;
            f16x8 vdat = *(const f16x8*)&Ds[row * DQ_STRIDE + cc];
            if (pr < 2) {
                f16* Out = (pr == 0) ? Qg : Kg;
                *(f16x8*)(Out + ((size_t)(b * NPOS + p0 + row)) * CDIM + q * 64 + cc) = vdat;
            } else {
                *(f16x8*)(Vg + ((size_t)(b * CDIM + q * 64 + row)) * NPOS + p0 + cc) = vdat;
            }
        }
        LBAR();
    }
}

// ---------------------------------------------------------------------------
// attn: R16 verbatim (proven 105.9us x3). grid 512, 256 thr = 4 waves,
// (256,2), 2 blocks/CU co-resident, bijective XCD swizzle. Per chunk: K+V
// reg-prefetch -> LDS commit; swapped QK^T (S^T in registers); in-register
// softmax with LSE cross-wave merge; P f16 tile -> LDS; PV from Vs+P
// ds_read_b128. 3 LDS-only barriers. Partial F fp32 [bq][half][256c][64p].
// ---------------------------------------------------------------------------
__global__ __launch_bounds__(256, 2) void attn_kernel(
    const f16* __restrict__ Qg, const f16* __restrict__ Kg, const f16* __restrict__ Vg,
    float* __restrict__ Fp)
{
    __shared__ f16   Ks[64 * QK_STRIDE];   // 33792 B  [key][c]
    __shared__ f16   Vs[256 * V_STRIDE];   // 36864 B  [c][j]
    __shared__ f16   Pl[64 * V_STRIDE];    //  9216 B  [p][key]
    __shared__ float RedM[2][64], RedS[2][64];  // 1024 B

    const int t    = threadIdx.x;
    const int L    = (int)((blockIdx.x & 7) * 64 + (blockIdx.x >> 3)); // XCD swizzle
    const int grp  = L >> 6;         // 0..7 = (b<<1 | half)
    const int b    = grp >> 1;
    const int half = grp & 1;
    const int qt   = L & 63;
    const int p0   = qt << 6;
    const int bq   = b * 64 + qt;
    const int w    = t >> 6;         // 0..3
    const int l    = t & 63;
    const int lm   = l & 31;
    const int lh   = l >> 5;
    const int spt  = w & 1;          // wave's p-tile
    const int skt  = w >> 1;         // wave's key-tile

    // Q fragments (MFMA B-operand; layout identical to A-operand)
    f16x8 qf[16];
    {
        const f16* qptr = Qg + (size_t)(b * NPOS + p0 + spt * 32 + lm) * CDIM + lh * 8;
        #pragma unroll
        for (int ks = 0; ks < 16; ++ks) qf[ks] = *(const f16x8*)(qptr + ks * 16);
    }

    // K prefetch registers (rows coalesced from Kg[n][c])
    const int kr = t >> 5, koff = (t & 31) * 8;
    f16x8 kreg[8];
    auto issue_k = [&](int ch) {
        const int i0 = ch * 64;
        #pragma unroll
        for (int r = 0; r < 8; ++r)
            kreg[r] = *(const f16x8*)(Kg + (size_t)(b * NPOS + i0 + r * 8 + kr) * CDIM + koff);
    };

    // V prefetch registers (128B-contiguous runs per c-row from Vg[c][n])
    const int vr = t >> 3;           // c row within each 32-row group
    const int vc = (t & 7) * 8;      // halfword col within chunk
    f16x8 vreg[8];
    auto issue_v = [&](int ch) {
        const int i0 = ch * 64;
        #pragma unroll
        for (int i = 0; i < 8; ++i)
            vreg[i] = *(const f16x8*)(Vg + (size_t)(b * CDIM + i * 32 + vr) * NPOS + i0 + vc);
    };

    issue_k(half * 32);
    issue_v(half * 32);

    f32x16 facc[4] = {};      // per-wave F acc: [ci=c-subtile(2)][pj=p-tile(2)]

    for (int it = 0; it < 32; ++it) {
        const int ch = half * 32 + it;

        // commit prefetched K to LDS, then issue next chunk's K loads
        #pragma unroll
        for (int r = 0; r < 8; ++r)
            *(f16x8*)&Ks[(r * 8 + kr) * QK_STRIDE + koff] = kreg[r];
        if (it < 31) issue_k(ch + 1);
        LBAR();   // A: Ks ready; prev PV's Vs/Pl reads done

        // commit prefetched V to LDS, then issue next chunk's V loads
        #pragma unroll
        for (int i = 0; i < 8; ++i)
            *(f16x8*)&Vs[(i * 32 + vr) * V_STRIDE + vc] = vreg[i];
        if (it < 31) issue_v(ch + 1);

        // S^T = K Q^T : D[m=key][n=p]; lane holds S^T[16 keys][p=spt*32+lm]
        f32x16 st = {};
        __builtin_amdgcn_s_setprio(1);
        #pragma unroll
        for (int ks = 0; ks < 16; ++ks) {
            f16x8 kf = *(const f16x8*)&Ks[(skt * 32 + lm) * QK_STRIDE + ks * 16 + lh * 8];
            st = __builtin_amdgcn_mfma_f32_32x32x16_f16(kf, qf[ks], st, 0, 0, 0);
        }
        __builtin_amdgcn_s_setprio(0);

        // in-register softmax over this key-tile (32 keys: 16 own + lh-partner)
        float mx = st[0];
        #pragma unroll
        for (int r = 1; r < 16; ++r) mx = fmaxf(mx, st[r]);
        mx = fmaxf(mx, __shfl_xor(mx, 32));
        float ss = 0.f;
        #pragma unroll
        for (int r = 0; r < 16; ++r) {
            float e = __expf(st[r] - mx);
            st[r] = e;
            ss += e;
        }
        ss += __shfl_xor(ss, 32);
        if (lh == 0) { RedM[skt][spt * 32 + lm] = mx; RedS[skt][spt * 32 + lm] = ss; }
        LBAR();   // B: Red exchange ready

        // LSE merge with partner key-tile wave -> full 64-key softmax
        float mo = RedM[skt ^ 1][spt * 32 + lm];
        float so = RedS[skt ^ 1][spt * 32 + lm];
        float M  = fmaxf(mx, mo);
        float S  = ss * __expf(mx - M) + so * __expf(mo - M);
        float scale = __expf(mx - M) * __builtin_amdgcn_rcpf(S);

        // P[key][p] f16 -> Pl[p][key]; lane's 16 keys = 4 runs of 4 consecutive
        #pragma unroll
        for (int rq = 0; rq < 4; ++rq) {
            f16x4 pk;
            #pragma unroll
            for (int q2 = 0; q2 < 4; ++q2) pk[q2] = (f16)(st[rq * 4 + q2] * scale);
            *(f16x4*)&Pl[(spt * 32 + lm) * V_STRIDE + skt * 32 + rq * 8 + lh * 4] = pk;
        }
        LBAR();   // C: Pl ready; Vs commits drained

        // F += V P : D[m=c][n=p]; A=Vs rows, B=Pl rows (both b128-contiguous)
        __builtin_amdgcn_s_setprio(1);
        #pragma unroll
        for (int kb = 0; kb < 4; ++kb) {
            f16x8 pf0 = *(const f16x8*)&Pl[lm * V_STRIDE + kb * 16 + lh * 8];
            f16x8 pf1 = *(const f16x8*)&Pl[(32 + lm) * V_STRIDE + kb * 16 + lh * 8];
            f16x8 va0 = *(const f16x8*)&Vs[(w * 64 + lm) * V_STRIDE + kb * 16 + lh * 8];
            f16x8 va1 = *(const f16x8*)&Vs[(w * 64 + 32 + lm) * V_STRIDE + kb * 16 + lh * 8];
            facc[0] = __builtin_amdgcn_mfma_f32_32x32x16_f16(va0, pf0, facc[0], 0, 0, 0);
            facc[1] = __builtin_amdgcn_mfma_f32_32x32x16_f16(va0, pf1, facc[1], 0, 0, 0);
            facc[2] = __builtin_amdgcn_mfma_f32_32x32x16_f16(va1, pf0, facc[2], 0, 0, 0);
            facc[3] = __builtin_amdgcn_mfma_f32_32x32x16_f16(va1, pf1, facc[3], 0, 0, 0);
        }
        __builtin_amdgcn_s_setprio(0);
    }

    // partial F out: Fp[bq][half][c][p] fp32
    float* dst = Fp + ((size_t)bq * 2 + half) * (CDIM * 64);
    #pragma unroll
    for (int ii = 0; ii < 2; ++ii)
        #pragma unroll
        for (int jj = 0; jj < 2; ++jj)
            #pragma unroll
            for (int r = 0; r < 16; ++r) {
                int c = w * 64 + ii * 32 + (r & 3) + 8 * (r >> 2) + 4 * lh;
                int p = jj * 32 + lm;
                dst[c * 64 + p] = facc[ii * 2 + jj][r];
            }
}

// ---------------------------------------------------------------------------
// merge_ln: grid 256 = (b<<6 | qtile), 256 thr. Sums the 2 half-partials
// into LDS, computes per-position mean/var over channels, writes normalized
// output. (unchanged, proven correct)
// ---------------------------------------------------------------------------
__global__ __launch_bounds__(256, 2) void merge_ln_kernel(
    const float* __restrict__ Fp, const float* __restrict__ ln_w,
    const float* __restrict__ ln_b, float* __restrict__ out)
{
    __shared__ float Fs[256 * F_STRIDE];          // 69632 B
    __shared__ float redS[16 * 64], redQ[16 * 64];
    __shared__ float lnw_s[256], lnb_s[256];
    __shared__ float mu_s[64], rs_s[64];

    const int t  = threadIdx.x;
    const int bq = blockIdx.x;
    const int b  = bq >> 6;
    const int p0 = (bq & 63) << 6;

    lnw_s[t] = ln_w[t]; lnb_s[t] = ln_b[t];

    const int pb = (t & 15) * 4;      // 4 consecutive positions
    const int cg = t >> 4;            // 16-channel group
    const float* base = Fp + (size_t)bq * 2 * (CDIM * 64);

    f32x4 s4 = {}, q4 = {};
    #pragma unroll 4
    for (int ci = 0; ci < 16; ++ci) {
        int c = cg * 16 + ci;
        size_t off = (size_t)c * 64 + pb;
        f32x4 v = *(const f32x4*)(base + off);
        v += *(const f32x4*)(base + (size_t)(CDIM * 64) + off);
        *(f32x4*)&Fs[c * F_STRIDE + pb] = v;
        s4 += v; q4 += v * v;
    }
    #pragma unroll
    for (int k2 = 0; k2 < 4; ++k2) {
        redS[cg * 64 + pb + k2] = s4[k2];
        redQ[cg * 64 + pb + k2] = q4[k2];
    }
    __syncthreads();
    if (t < 64) {
        float ss = 0.f, qq = 0.f;
        #pragma unroll
        for (int g2 = 0; g2 < 16; ++g2) { ss += redS[g2 * 64 + t]; qq += redQ[g2 * 64 + t]; }
        float mean = ss * (1.0f / 256.0f);
        float var  = qq * (1.0f / 256.0f) - mean * mean;
        mu_s[t] = mean;
        rs_s[t] = rsqrtf(var + EPSV);
    }
    __syncthreads();
    const int p   = t & 63;
    const int cg2 = t >> 6;
    const float mu = mu_s[p], rs = rs_s[p];
    float* dst = out + (size_t)b * CDIM * NPOS + p0 + p;
    #pragma unroll 4
    for (int ci = 0; ci < 64; ++ci) {
        int c = cg2 * 64 + ci;
        dst[(size_t)c * NPOS] = (Fs[c * F_STRIDE + p] - mu) * rs * lnw_s[c] + lnb_s[c];
    }
}

// ---------------------------------------------------------------------------
extern "C" void kernel_launch(void* const* d_in, const int* in_sizes, int n_in,
                              void* d_out, int out_size, void* d_ws, size_t ws_size,
                              hipStream_t stream)
{
    const float* x1  = (const float*)d_in[0];
    const float* x2  = (const float*)d_in[1];
    const float* qw  = (const float*)d_in[2];
    const float* qb  = (const float*)d_in[3];
    const float* kw  = (const float*)d_in[4];
    const float* kb  = (const float*)d_in[5];
    const float* vw  = (const float*)d_in[6];
    const float* vb  = (const float*)d_in[7];
    const float* lnw = (const float*)d_in[8];
    const float* lnb = (const float*)d_in[9];

    const size_t tsz = (size_t)BATCH * NPOS * CDIM;
    f16* Qg  = (f16*)d_ws;
    f16* Kg  = Qg + tsz;
    f16* Vg  = Kg + tsz;
    f16* Wf  = Vg + tsz;                          // 384 KB fragment-major W
    float* Fp = (float*)(Wf + 3 * CDIM * CDIM);   // 32 MB fp32; total ws ~57 MB

    wconv_kernel<<<24, 256, 0, stream>>>(qw, kw, vw, Wf);
    gemm_kernel<<<768, 256, 0, stream>>>(x1, x2, Wf, qb, kb, vb, Qg, Kg, Vg);
    attn_kernel<<<512, 256, 0, stream>>>(Qg, Kg, Vg, Fp);
    merge_ln_kernel<<<256, 256, 0, stream>>>(Fp, lnw, lnb, (float*)d_out);
}